// Round 6
// baseline (130.208 us; speedup 1.0000x reference)
//
#include <hip/hip_runtime.h>
#include <stdint.h>

#define NN 8192   // nodes
#define NE 8192   // edges
#define DIM 128
#define NL 17
#define SPLITK 8
#define KCHUNK (NN / SPLITK)   // 1024
#define NIT (KCHUNK / 32)      // 32
#define TILE_E 64
#define NT_MAX 160             // actual tiles <= 128 + 17 = 145

typedef float f32x4 __attribute__((ext_vector_type(4)));
typedef short short8 __attribute__((ext_vector_type(8)));

// ---- workspace layout (bytes) ----
#define WS_XHI    0ull                              // 2 MB  (xT blocked hi bf16)
#define WS_XLO    (2ull << 20)                      // 2 MB  (xT blocked lo bf16)
#define WS_COLSUM (4ull << 20)                      // 64 KB (128 x 128 f32)
#define WS_C0E    ((4ull << 20) + (64ull << 10))    // 8.5 KB
#define WS_ELIST  ((4ull << 20) + (80ull << 10))    // 32 KB (8192 int)
#define WS_TMAP   ((4ull << 20) + (112ull << 10))   // 2.5 KB (int4 per tile)
#define WS_NT     ((4ull << 20) + (120ull << 10))   // 4 B
#define WS_WT     (5ull << 20)                      // 1.0625 MB (17 x 64KB W1 hi/lo bf16)
#define WS_PART   (8ull << 20)                      // 32 MB (SPLITK x E x D f32)

#define GPTR(p) ((const __attribute__((address_space(1))) uint32_t*)(p))
#define LPTR(p) ((__attribute__((address_space(3))) uint32_t*)(p))

// Round-to-nearest-even f32 -> bf16 bits.
__device__ __forceinline__ uint16_t f32_to_bf16(float v) {
  uint32_t u = __builtin_bit_cast(uint32_t, v);
  u += 0x7fffu + ((u >> 16) & 1u);
  return (uint16_t)(u >> 16);
}
__device__ __forceinline__ float bf16_to_f32(uint16_t h) {
  uint32_t u = ((uint32_t)h) << 16;
  return __builtin_bit_cast(float, u);
}

// Prep: column sums of x (for x0), and x transposed into k-blocked bf16 hi/lo:
// xTb[kblk][d][kk] with kblk = k/32, kk = k%32. 128 blocks x 64 nodes.
__global__ __launch_bounds__(256) void k_prep(const float* __restrict__ x,
                                              uint16_t* __restrict__ xhi,
                                              uint16_t* __restrict__ xlo,
                                              float* __restrict__ colsum) {
  __shared__ float xs[64][129];
  const int t = threadIdx.x;
  const int b = blockIdx.x;  // nodes b*64 .. b*64+63
  const float4* xg = (const float4*)(x + (size_t)b * 64 * DIM);
  for (int r = 0; r < 8; ++r) {
    int f = t + r * 256;           // float4 index within tile
    float4 v = xg[f];
    int n = f >> 5;
    int d0 = (f & 31) * 4;
    xs[n][d0] = v.x; xs[n][d0 + 1] = v.y; xs[n][d0 + 2] = v.z; xs[n][d0 + 3] = v.w;
  }
  __syncthreads();
  if (t < 128) {
    float s = 0.f;
    for (int n = 0; n < 64; ++n) s += xs[n][t];
    colsum[b * DIM + t] = s;
  }
  // 2048 16B chunks: q = [hl(1)][kb(1)][d(7)][c(2)]
  for (int r = 0; r < 8; ++r) {
    int q = t + r * 256;
    int c = q & 3;
    int d = (q >> 2) & 127;
    int kb = (q >> 9) & 1;
    int hl = q >> 10;
    int kk0 = c * 8;
    uint32_t w[4];
    for (int j = 0; j < 4; ++j) {
      uint16_t h0, h1;
      {
        float v = xs[kb * 32 + kk0 + 2 * j][d];
        uint16_t hi = f32_to_bf16(v);
        h0 = hl ? f32_to_bf16(v - bf16_to_f32(hi)) : hi;
      }
      {
        float v = xs[kb * 32 + kk0 + 2 * j + 1][d];
        uint16_t hi = f32_to_bf16(v);
        h1 = hl ? f32_to_bf16(v - bf16_to_f32(hi)) : hi;
      }
      w[j] = (uint32_t)h0 | ((uint32_t)h1 << 16);
    }
    int kblk = b * 2 + kb;
    uint16_t* dst = (hl ? xlo : xhi) + ((size_t)(kblk * 128 + d)) * 32 + kk0;
    *(uint4*)dst = make_uint4(w[0], w[1], w[2], w[3]);
  }
}

// Fused aux kernel. Blocks 0..16: c0e[l]. Blocks 17..33: W1[l] -> hi/lo bf16
// fragment-blocked table. Block 34: edge bucketing by order.
__global__ __launch_bounds__(256) void k_aux(const float* __restrict__ colsum,
                                             const float* __restrict__ W,
                                             const float* __restrict__ Bb,
                                             const int* __restrict__ orders,
                                             float* __restrict__ c0e,
                                             uint16_t* __restrict__ Wt,
                                             int* __restrict__ elist,
                                             int4* __restrict__ tmap,
                                             int* __restrict__ n_tiles) {
  __shared__ float x0[DIM];
  __shared__ int hist[NL], cur[NL];
  const int t = threadIdx.x;
  const int bid = blockIdx.x;
  if (bid < 17) {
    // c0e[l][j] = x0 @ W[0,l] + B[l]
    if (t < 128) {
      float s = 0.f;
      for (int b = 0; b < 128; ++b) s += colsum[b * DIM + t];
      x0[t] = s * (1.0f / NN);
    }
    __syncthreads();
    if (t < 128) {
      const float* W0l = W + (size_t)bid * DIM * DIM;
      float acc = Bb[bid * DIM + t];
#pragma unroll 8
      for (int i = 0; i < DIM; ++i) acc += x0[i] * W0l[(size_t)i * DIM + t];
      c0e[bid * DIM + t] = acc;
    }
  } else if (bid < 34) {
    // Wt[l]: element (hl,kblk,c,j,kk8) at l*32768 + hl*16384 + kblk*4096 +
    // c*1024 + j*8 + kk8  (uint16 elements); value = bf16 of W[1][l][k][j],
    // k = kblk*32 + c*8 + kk8.
    const int l = bid - 17;
    const float* W1l = W + (size_t)(NL + l) * DIM * DIM;
    uint16_t* base = Wt + (size_t)l * 32768;
#pragma unroll
    for (int r = 0; r < 8; ++r) {
      int q = t + r * 256;
      int j = q & 127;
      int c = (q >> 7) & 3;
      int kblk = q >> 9;
      int k0 = kblk * 32 + c * 8;
      uint32_t wh[4], wl[4];
#pragma unroll
      for (int p = 0; p < 4; ++p) {
        float v0 = W1l[(size_t)(k0 + 2 * p) * DIM + j];
        float v1 = W1l[(size_t)(k0 + 2 * p + 1) * DIM + j];
        uint16_t h0 = f32_to_bf16(v0);
        uint16_t l0 = f32_to_bf16(v0 - bf16_to_f32(h0));
        uint16_t h1 = f32_to_bf16(v1);
        uint16_t l1 = f32_to_bf16(v1 - bf16_to_f32(h1));
        wh[p] = (uint32_t)h0 | ((uint32_t)h1 << 16);
        wl[p] = (uint32_t)l0 | ((uint32_t)l1 << 16);
      }
      uint16_t* dst = base + kblk * 4096 + c * 1024 + j * 8;
      *(uint4*)dst = make_uint4(wh[0], wh[1], wh[2], wh[3]);
      *(uint4*)(dst + 16384) = make_uint4(wl[0], wl[1], wl[2], wl[3]);
    }
  } else {
    // bucket edges by order; build 64-edge tile map
    if (t < NL) hist[t] = 0;
    __syncthreads();
    for (int i = t; i < NE; i += 256) atomicAdd(&hist[orders[i]], 1);
    __syncthreads();
    if (t == 0) {
      int run = 0, nt = 0;
      for (int l = 0; l < NL; ++l) {
        cur[l] = run;
        int c = hist[l];
        for (int off = 0; off < c; off += TILE_E) {
          int cc = c - off; if (cc > TILE_E) cc = TILE_E;
          tmap[nt++] = make_int4(l, run + off, cc, 0);
        }
        run += c;
      }
      *n_tiles = nt;
    }
    __syncthreads();
    for (int i = t; i < NE; i += 256) {
      int l = orders[i];
      int pos = atomicAdd(&cur[l], 1);
      elist[pos] = i;
    }
  }
}

// Big MFMA GEMM: part[s][e][d] = sum_{k in chunk s} inc[k][e] * x[k][d].
// Round-3 form: double-buffered B via global_load_lds(16B), A-register
// prefetch one iteration ahead, one __syncthreads per iteration (compiler-
// scheduled waits; no sched_barrier pinning).
__global__ __launch_bounds__(256, 2) void k_gemm(const float* __restrict__ inc,
                                                 const uint16_t* __restrict__ xhi,
                                                 const uint16_t* __restrict__ xlo,
                                                 float* __restrict__ part) {
  __shared__ uint16_t Bs[2][8192];
  const int t = threadIdx.x;
  const int mb = blockIdx.x & 63;
  const int s = blockIdx.x >> 6;
  const int e0 = mb * 128;
  const int w = t >> 6;
  const int lane = t & 63;
  const int lm = lane & 15;
  const int lk = lane >> 4;          // 0..3
  const int kbase = s * KCHUNK;
  const int kb0 = kbase >> 5;        // first kblk

  f32x4 acc[2][8];
#pragma unroll
  for (int a = 0; a < 2; ++a)
#pragma unroll
    for (int b = 0; b < 8; ++b) acc[a][b] = (f32x4){0.f, 0.f, 0.f, 0.f};

  const char* hbase = (const char*)xhi;
  const char* lbase = (const char*)xlo;

#define STAGE(buf, kblk) { \
    const char* hsrc = hbase + (size_t)(kblk) * 8192; \
    const char* lsrc = lbase + (size_t)(kblk) * 8192; \
    char* dbase = (char*)&Bs[buf][0]; \
    _Pragma("unroll") \
    for (int j = 0; j < 4; ++j) { \
      int q = w + 4 * j; \
      const char* src = (q < 8) ? (hsrc + q * 1024) : (lsrc + (q - 8) * 1024); \
      __builtin_amdgcn_global_load_lds(GPTR(src + lane * 16), \
                                       LPTR(dbase + q * 1024), 16, 0, 0); \
    } }

#define LOADA(u, it) { \
    const int k0_ = kbase + (it) * 32; \
    _Pragma("unroll") \
    for (int fm = 0; fm < 2; ++fm) { \
      const float* ap = inc + (size_t)(k0_ + lk * 8) * NE + (e0 + w * 32 + fm * 16 + lm); \
      _Pragma("unroll") \
      for (int j = 0; j < 8; ++j) \
        u[fm][j] = __builtin_bit_cast(uint32_t, ap[(size_t)j * NE]); \
    } }

#define COMPUTE(buf, u) { \
    short8 afr[2]; \
    _Pragma("unroll") \
    for (int fm = 0; fm < 2; ++fm) { \
      union { uint32_t w4[4]; short8 s8; } pk; \
      _Pragma("unroll") \
      for (int j = 0; j < 4; ++j) \
        pk.w4[j] = (u[fm][2 * j + 1] & 0xffff0000u) | (u[fm][2 * j] >> 16); \
      afr[fm] = pk.s8; \
    } \
    _Pragma("unroll") \
    for (int fn = 0; fn < 8; ++fn) { \
      int n = fn * 16 + lm; \
      short8 bh = *(const short8*)&Bs[buf][n * 32 + lk * 8]; \
      short8 bl = *(const short8*)&Bs[buf][4096 + n * 32 + lk * 8]; \
      acc[0][fn] = __builtin_amdgcn_mfma_f32_16x16x32_bf16(afr[0], bh, acc[0][fn], 0, 0, 0); \
      acc[1][fn] = __builtin_amdgcn_mfma_f32_16x16x32_bf16(afr[1], bh, acc[1][fn], 0, 0, 0); \
      acc[0][fn] = __builtin_amdgcn_mfma_f32_16x16x32_bf16(afr[0], bl, acc[0][fn], 0, 0, 0); \
      acc[1][fn] = __builtin_amdgcn_mfma_f32_16x16x32_bf16(afr[1], bl, acc[1][fn], 0, 0, 0); \
    } }

  uint32_t ua[2][8], ub[2][8];
  STAGE(0, kb0);
  LOADA(ua, 0);
  __syncthreads();               // Bs[0] staged, ua ready

  for (int it2 = 0; it2 < NIT; it2 += 2) {
    if (it2 + 1 < NIT) { STAGE(1, kb0 + it2 + 1); LOADA(ub, it2 + 1); }
    COMPUTE(0, ua);
    __syncthreads();
    if (it2 + 2 < NIT) { STAGE(0, kb0 + it2 + 2); LOADA(ua, it2 + 2); }
    COMPUTE(1, ub);
    __syncthreads();
  }

  float* pbase = part + (size_t)s * NE * DIM;
#pragma unroll
  for (int fm = 0; fm < 2; ++fm)
#pragma unroll
    for (int fn = 0; fn < 8; ++fn)
#pragma unroll
      for (int r = 0; r < 4; ++r) {
        int e = e0 + w * 32 + fm * 16 + lk * 4 + r;
        int d = fn * 16 + lm;
        pbase[(size_t)e * DIM + d] = acc[fm][fn][r];
      }
#undef STAGE
#undef LOADA
#undef COMPUTE
}

// Bucketed MFMA edge kernel: one block per 64-edge same-order tile.
// Reduce split-K partials (f32, fixed order), normalize, convert to hi/lo
// bf16 in LDS fragment layout; MFMA against fragment-blocked W table read
// direct from global (L2-hot); add c0e; write out_e. Per-edge result is
// independent of bucket slot -> deterministic outputs.
__global__ __launch_bounds__(256) void k_edgeM(const float* __restrict__ part,
                                               const int* __restrict__ elist,
                                               const int4* __restrict__ tmap,
                                               const int* __restrict__ n_tiles,
                                               const float* __restrict__ norm,
                                               const uint16_t* __restrict__ Wt,
                                               const float* __restrict__ c0e,
                                               float* __restrict__ out_e) {
  __shared__ uint16_t xh_s[4][4][TILE_E][8];  // [kblk][c][m][kk8] 16 KB
  __shared__ uint16_t xl_s[4][4][TILE_E][8];  // 16 KB
  __shared__ int el[TILE_E];
  const int t = threadIdx.x;
  if (blockIdx.x >= *n_tiles) return;
  const int4 ti = tmap[blockIdx.x];
  const int l = ti.x, start = ti.y, cnt = ti.z;

  if (t < TILE_E) el[t] = elist[start + (t < cnt ? t : cnt - 1)];
  __syncthreads();

  // reduce split-K partials: thread -> (m = t&63, kc = t>>6 = wave id)
  {
    const int m = t & 63;
    const int kc = t >> 6;
    const int e = el[m];
    const float rn = 1.0f / norm[e];
    f32x4 a[8];
#pragma unroll
    for (int j = 0; j < 8; ++j) a[j] = (f32x4){0.f, 0.f, 0.f, 0.f};
#pragma unroll
    for (int s = 0; s < SPLITK; ++s) {
      const float* pr = part + ((size_t)s * NE + e) * DIM + kc * 32;
#pragma unroll
      for (int j = 0; j < 8; ++j) a[j] += *(const f32x4*)(pr + j * 4);
    }
    float av[32];
#pragma unroll
    for (int j = 0; j < 8; ++j) {
      av[4 * j] = a[j][0]; av[4 * j + 1] = a[j][1];
      av[4 * j + 2] = a[j][2]; av[4 * j + 3] = a[j][3];
    }
#pragma unroll
    for (int i = 0; i < 32; ++i) av[i] *= rn;
#pragma unroll
    for (int cl = 0; cl < 4; ++cl) {
      uint32_t wh[4], wl[4];
#pragma unroll
      for (int p = 0; p < 4; ++p) {
        float v0 = av[cl * 8 + 2 * p], v1 = av[cl * 8 + 2 * p + 1];
        uint16_t h0 = f32_to_bf16(v0);
        uint16_t l0 = f32_to_bf16(v0 - bf16_to_f32(h0));
        uint16_t h1 = f32_to_bf16(v1);
        uint16_t l1 = f32_to_bf16(v1 - bf16_to_f32(h1));
        wh[p] = (uint32_t)h0 | ((uint32_t)h1 << 16);
        wl[p] = (uint32_t)l0 | ((uint32_t)l1 << 16);
      }
      *(uint4*)&xh_s[kc][cl][m][0] = make_uint4(wh[0], wh[1], wh[2], wh[3]);
      *(uint4*)&xl_s[kc][cl][m][0] = make_uint4(wl[0], wl[1], wl[2], wl[3]);
    }
  }
  __syncthreads();

  // MFMA: wave w owns cols n0 = w*32 .. +31 (fn = 0..1); fm = 0..3 (all M).
  const int w = t >> 6;
  const int lane = t & 63;
  const int lm = lane & 15;
  const int lk = lane >> 4;
  const int n0 = w * 32;
  const uint16_t* WtL = Wt + (size_t)l * 32768;
  f32x4 acc[4][2];
#pragma unroll
  for (int fm = 0; fm < 4; ++fm)
#pragma unroll
    for (int fn = 0; fn < 2; ++fn) acc[fm][fn] = (f32x4){0.f, 0.f, 0.f, 0.f};

#pragma unroll
  for (int kblk = 0; kblk < 4; ++kblk) {
    short8 ah[4], al8[4];
#pragma unroll
    for (int fm = 0; fm < 4; ++fm) {
      ah[fm]  = *(const short8*)&xh_s[kblk][lk][fm * 16 + lm][0];
      al8[fm] = *(const short8*)&xl_s[kblk][lk][fm * 16 + lm][0];
    }
#pragma unroll
    for (int fn = 0; fn < 2; ++fn) {
      const int j = n0 + fn * 16 + lm;
      short8 bh = *(const short8*)(WtL + kblk * 4096 + lk * 1024 + j * 8);
      short8 bl = *(const short8*)(WtL + 16384 + kblk * 4096 + lk * 1024 + j * 8);
#pragma unroll
      for (int fm = 0; fm < 4; ++fm) {
        acc[fm][fn] = __builtin_amdgcn_mfma_f32_16x16x32_bf16(ah[fm], bh, acc[fm][fn], 0, 0, 0);
        acc[fm][fn] = __builtin_amdgcn_mfma_f32_16x16x32_bf16(ah[fm], bl, acc[fm][fn], 0, 0, 0);
        acc[fm][fn] = __builtin_amdgcn_mfma_f32_16x16x32_bf16(al8[fm], bh, acc[fm][fn], 0, 0, 0);
      }
    }
  }

#pragma unroll
  for (int fm = 0; fm < 4; ++fm)
#pragma unroll
    for (int fn = 0; fn < 2; ++fn) {
      const int j = n0 + fn * 16 + lm;
      const float cj = c0e[l * DIM + j];
#pragma unroll
      for (int r = 0; r < 4; ++r) {
        const int mrow = fm * 16 + lk * 4 + r;
        if (mrow < cnt)
          out_e[(size_t)el[mrow] * DIM + j] = acc[fm][fn][r] + cj;
      }
    }
}

// Node side: out_v[n] = c0e[1] + x[n] @ W[1,1]. 4x4 register tile per thread.
__global__ __launch_bounds__(256) void k_node(const float* __restrict__ x,
                                              const float* __restrict__ W,
                                              const float* __restrict__ c0e,
                                              float* __restrict__ out_v) {
  __shared__ float xr[32][DIM];
  const int t = threadIdx.x;
  const int row0 = blockIdx.x * 32;
  for (int i = t; i < 32 * DIM; i += 256)
    xr[i >> 7][i & 127] = x[(size_t)row0 * DIM + i];
  const int tx = t & 31;
  const int ty = t >> 5;
  const float4* W4 = (const float4*)(W + (size_t)(NL + 1) * DIM * DIM);
  const float4 cv = ((const float4*)(c0e + DIM))[tx];
  float4 o0 = cv, o1 = cv, o2 = cv, o3 = cv;
  __syncthreads();
#pragma unroll 4
  for (int k = 0; k < DIM; ++k) {
    float4 w = W4[k * 32 + tx];
    float a0 = xr[ty * 4 + 0][k];
    float a1 = xr[ty * 4 + 1][k];
    float a2 = xr[ty * 4 + 2][k];
    float a3 = xr[ty * 4 + 3][k];
    o0.x += a0 * w.x; o0.y += a0 * w.y; o0.z += a0 * w.z; o0.w += a0 * w.w;
    o1.x += a1 * w.x; o1.y += a1 * w.y; o1.z += a1 * w.z; o1.w += a1 * w.w;
    o2.x += a2 * w.x; o2.y += a2 * w.y; o2.z += a2 * w.z; o2.w += a2 * w.w;
    o3.x += a3 * w.x; o3.y += a3 * w.y; o3.z += a3 * w.z; o3.w += a3 * w.w;
  }
  float4* out4 = (float4*)(out_v + (size_t)(row0 + ty * 4) * DIM);
  out4[0 * 32 + tx] = o0;
  out4[1 * 32 + tx] = o1;
  out4[2 * 32 + tx] = o2;
  out4[3 * 32 + tx] = o3;
}

extern "C" void kernel_launch(void* const* d_in, const int* in_sizes, int n_in,
                              void* d_out, int out_size, void* d_ws, size_t ws_size,
                              hipStream_t stream) {
  const float* x      = (const float*)d_in[0];
  const float* inc    = (const float*)d_in[1];
  const int*   orders = (const int*)d_in[2];
  const float* norm   = (const float*)d_in[3];
  const float* W      = (const float*)d_in[4];
  const float* Bb     = (const float*)d_in[5];
  float* out_v = (float*)d_out;
  float* out_e = (float*)d_out + (size_t)NN * DIM;

  char* ws = (char*)d_ws;
  uint16_t* xhi   = (uint16_t*)(ws + WS_XHI);
  uint16_t* xlo   = (uint16_t*)(ws + WS_XLO);
  float* colsum   = (float*)(ws + WS_COLSUM);
  float* c0e      = (float*)(ws + WS_C0E);
  int*   elist    = (int*)(ws + WS_ELIST);
  int4*  tmap     = (int4*)(ws + WS_TMAP);
  int*   n_tiles  = (int*)(ws + WS_NT);
  uint16_t* Wt    = (uint16_t*)(ws + WS_WT);
  float* part     = (float*)(ws + WS_PART);

  k_prep<<<128, 256, 0, stream>>>(x, xhi, xlo, colsum);
  k_aux<<<35, 256, 0, stream>>>(colsum, W, Bb, orders, c0e, Wt, elist, tmap, n_tiles);
  k_gemm<<<512, 256, 0, stream>>>(inc, xhi, xlo, part);
  k_edgeM<<<NT_MAX, 256, 0, stream>>>(part, elist, tmap, n_tiles, norm, Wt, c0e, out_e);
  k_node<<<NN / 32, 256, 0, stream>>>(x, W, c0e, out_v);
}

// Round 7
// 114.157 us; speedup vs baseline: 1.1406x; 1.1406x over previous
//
#include <hip/hip_runtime.h>
#include <stdint.h>

#define NN 8192   // nodes
#define NE 8192   // edges
#define DIM 128
#define NL 17
#define SPLITK 8
#define KCHUNK (NN / SPLITK)   // 1024
#define NIT (KCHUNK / 32)      // 32

typedef float f32x4 __attribute__((ext_vector_type(4)));
typedef short short8 __attribute__((ext_vector_type(8)));

// ---- workspace layout (bytes) ----
#define WS_XHI    0ull                              // 2 MB  (xT blocked hi bf16)
#define WS_COLSUM (4ull << 20)                      // 64 KB (128 x 128 f32)
#define WS_C0E    ((4ull << 20) + (64ull << 10))    // 8.5 KB
#define WS_PART   (8ull << 20)                      // 32 MB (SPLITK x E x D f32)

#define GPTR(p) ((const __attribute__((address_space(1))) uint32_t*)(p))
#define LPTR(p) ((__attribute__((address_space(3))) uint32_t*)(p))

// Round-to-nearest-even f32 -> bf16 bits.
__device__ __forceinline__ uint16_t f32_to_bf16(float v) {
  uint32_t u = __builtin_bit_cast(uint32_t, v);
  u += 0x7fffu + ((u >> 16) & 1u);
  return (uint16_t)(u >> 16);
}

// Prep: column sums of x (for x0), and x transposed into k-blocked bf16:
// xhi[kblk][d][kk] with kblk = k/32, kk = k%32. 128 blocks x 64 nodes.
// bf16 quantization of x is safe: the /norm (~82) in the edge mean divides
// the error to ~3e-4 absolute, far under the 7.8e-3 reference floor.
__global__ __launch_bounds__(256) void k_prep(const float* __restrict__ x,
                                              uint16_t* __restrict__ xhi,
                                              float* __restrict__ colsum) {
  __shared__ float xs[64][129];
  const int t = threadIdx.x;
  const int b = blockIdx.x;  // nodes b*64 .. b*64+63
  const float4* xg = (const float4*)(x + (size_t)b * 64 * DIM);
  for (int r = 0; r < 8; ++r) {
    int f = t + r * 256;           // float4 index within tile
    float4 v = xg[f];
    int n = f >> 5;
    int d0 = (f & 31) * 4;
    xs[n][d0] = v.x; xs[n][d0 + 1] = v.y; xs[n][d0 + 2] = v.z; xs[n][d0 + 3] = v.w;
  }
  __syncthreads();
  if (t < 128) {
    float s = 0.f;
    for (int n = 0; n < 64; ++n) s += xs[n][t];
    colsum[b * DIM + t] = s;
  }
  // 1024 16B chunks: q = [kb(1)][d(7)][c(2)]
  for (int r = 0; r < 4; ++r) {
    int q = t + r * 256;
    int c = q & 3;
    int d = (q >> 2) & 127;
    int kb = q >> 9;
    int kk0 = c * 8;
    uint32_t w[4];
    for (int j = 0; j < 4; ++j) {
      uint16_t h0 = f32_to_bf16(xs[kb * 32 + kk0 + 2 * j][d]);
      uint16_t h1 = f32_to_bf16(xs[kb * 32 + kk0 + 2 * j + 1][d]);
      w[j] = (uint32_t)h0 | ((uint32_t)h1 << 16);
    }
    int kblk = b * 2 + kb;
    uint16_t* dst = xhi + ((size_t)(kblk * 128 + d)) * 32 + kk0;
    *(uint4*)dst = make_uint4(w[0], w[1], w[2], w[3]);
  }
}

// c0e[l][j] = x0 @ W[0,l] + B[l]; c0e[1] doubles as node-side constant.
__global__ __launch_bounds__(128) void k_c0e(const float* __restrict__ colsum,
                                             const float* __restrict__ W,
                                             const float* __restrict__ Bb,
                                             float* __restrict__ c0e) {
  __shared__ float x0[DIM];
  const int j = threadIdx.x;
  float s = 0.f;
  for (int b = 0; b < 128; ++b) s += colsum[b * DIM + j];
  x0[j] = s * (1.0f / NN);
  __syncthreads();
  const int l = blockIdx.x;
  const float* W0l = W + (size_t)l * DIM * DIM;
  float acc = Bb[l * DIM + j];
#pragma unroll 8
  for (int i = 0; i < DIM; ++i) acc += x0[i] * W0l[(size_t)i * DIM + j];
  c0e[l * DIM + j] = acc;
}

// Big MFMA GEMM: part[s][e][d] = sum_{k in chunk s} inc[k][e] * xhi[k][d].
// Single bf16 stream (inc exact in bf16; xhi quantization harmless after
// /norm). Double-buffered B via global_load_lds(16B), A-register prefetch
// one iteration ahead, one __syncthreads per iteration.
__global__ __launch_bounds__(256, 2) void k_gemm(const float* __restrict__ inc,
                                                 const uint16_t* __restrict__ xhi,
                                                 float* __restrict__ part) {
  __shared__ uint16_t Bs[2][4096];   // 8 KB per buffer, 16 KB total
  const int t = threadIdx.x;
  const int mb = blockIdx.x & 63;
  const int s = blockIdx.x >> 6;
  const int e0 = mb * 128;
  const int w = t >> 6;
  const int lane = t & 63;
  const int lm = lane & 15;
  const int lk = lane >> 4;          // 0..3
  const int kbase = s * KCHUNK;
  const int kb0 = kbase >> 5;        // first kblk

  f32x4 acc[2][8];
#pragma unroll
  for (int a = 0; a < 2; ++a)
#pragma unroll
    for (int b = 0; b < 8; ++b) acc[a][b] = (f32x4){0.f, 0.f, 0.f, 0.f};

  const char* hbase = (const char*)xhi;

#define STAGE(buf, kblk) { \
    const char* hsrc = hbase + (size_t)(kblk) * 8192; \
    char* dbase = (char*)&Bs[buf][0]; \
    _Pragma("unroll") \
    for (int j = 0; j < 2; ++j) { \
      int q = w + 4 * j; \
      __builtin_amdgcn_global_load_lds(GPTR(hsrc + q * 1024 + lane * 16), \
                                       LPTR(dbase + q * 1024), 16, 0, 0); \
    } }

#define LOADA(u, it) { \
    const int k0_ = kbase + (it) * 32; \
    _Pragma("unroll") \
    for (int fm = 0; fm < 2; ++fm) { \
      const float* ap = inc + (size_t)(k0_ + lk * 8) * NE + (e0 + w * 32 + fm * 16 + lm); \
      _Pragma("unroll") \
      for (int j = 0; j < 8; ++j) \
        u[fm][j] = __builtin_bit_cast(uint32_t, ap[(size_t)j * NE]); \
    } }

#define COMPUTE(buf, u) { \
    short8 afr[2]; \
    _Pragma("unroll") \
    for (int fm = 0; fm < 2; ++fm) { \
      union { uint32_t w4[4]; short8 s8; } pk; \
      _Pragma("unroll") \
      for (int j = 0; j < 4; ++j) \
        pk.w4[j] = (u[fm][2 * j + 1] & 0xffff0000u) | (u[fm][2 * j] >> 16); \
      afr[fm] = pk.s8; \
    } \
    _Pragma("unroll") \
    for (int fn = 0; fn < 8; ++fn) { \
      int n = fn * 16 + lm; \
      short8 bh = *(const short8*)&Bs[buf][n * 32 + lk * 8]; \
      acc[0][fn] = __builtin_amdgcn_mfma_f32_16x16x32_bf16(afr[0], bh, acc[0][fn], 0, 0, 0); \
      acc[1][fn] = __builtin_amdgcn_mfma_f32_16x16x32_bf16(afr[1], bh, acc[1][fn], 0, 0, 0); \
    } }

  uint32_t ua[2][8], ub[2][8];
  STAGE(0, kb0);
  LOADA(ua, 0);
  __syncthreads();               // Bs[0] staged, ua ready

  for (int it2 = 0; it2 < NIT; it2 += 2) {
    if (it2 + 1 < NIT) { STAGE(1, kb0 + it2 + 1); LOADA(ub, it2 + 1); }
    COMPUTE(0, ua);
    __syncthreads();
    if (it2 + 2 < NIT) { STAGE(0, kb0 + it2 + 2); LOADA(ua, it2 + 2); }
    COMPUTE(1, ub);
    __syncthreads();
  }

  float* pbase = part + (size_t)s * NE * DIM;
#pragma unroll
  for (int fm = 0; fm < 2; ++fm)
#pragma unroll
    for (int fn = 0; fn < 8; ++fn)
#pragma unroll
      for (int r = 0; r < 4; ++r) {
        int e = e0 + w * 32 + fm * 16 + lk * 4 + r;
        int d = fn * 16 + lm;
        pbase[(size_t)e * DIM + d] = acc[fm][fn][r];
      }
#undef STAGE
#undef LOADA
#undef COMPUTE
}

// Per-edge: reduce split-K partials, normalize, matvec with W[1,order] + c0e.
__global__ __launch_bounds__(128) void k_edge2(const float* __restrict__ part,
                                               const int* __restrict__ orders,
                                               const float* __restrict__ norm,
                                               const float* __restrict__ W,
                                               const float* __restrict__ c0e,
                                               float* __restrict__ out_e) {
  __shared__ float xl[DIM];
  const int t = threadIdx.x;
  const int e = blockIdx.x;
  float s = 0.f;
#pragma unroll
  for (int k = 0; k < SPLITK; ++k)
    s += part[(size_t)k * NE * DIM + (size_t)e * DIM + t];
  xl[t] = s / norm[e];
  __syncthreads();
  const int l = orders[e];
  const float* W1l = W + (size_t)(NL + l) * DIM * DIM;
  float o = c0e[l * DIM + t];
#pragma unroll 8
  for (int i = 0; i < DIM; ++i) o += xl[i] * W1l[(size_t)i * DIM + t];
  out_e[(size_t)e * DIM + t] = o;
}

// Node side: out_v[n] = c0e[1] + x[n] @ W[1,1]. 4x4 register tile per thread.
__global__ __launch_bounds__(256) void k_node(const float* __restrict__ x,
                                              const float* __restrict__ W,
                                              const float* __restrict__ c0e,
                                              float* __restrict__ out_v) {
  __shared__ float xr[32][DIM];
  const int t = threadIdx.x;
  const int row0 = blockIdx.x * 32;
  for (int i = t; i < 32 * DIM; i += 256)
    xr[i >> 7][i & 127] = x[(size_t)row0 * DIM + i];
  const int tx = t & 31;
  const int ty = t >> 5;
  const float4* W4 = (const float4*)(W + (size_t)(NL + 1) * DIM * DIM);
  const float4 cv = ((const float4*)(c0e + DIM))[tx];
  float4 o0 = cv, o1 = cv, o2 = cv, o3 = cv;
  __syncthreads();
#pragma unroll 4
  for (int k = 0; k < DIM; ++k) {
    float4 w = W4[k * 32 + tx];
    float a0 = xr[ty * 4 + 0][k];
    float a1 = xr[ty * 4 + 1][k];
    float a2 = xr[ty * 4 + 2][k];
    float a3 = xr[ty * 4 + 3][k];
    o0.x += a0 * w.x; o0.y += a0 * w.y; o0.z += a0 * w.z; o0.w += a0 * w.w;
    o1.x += a1 * w.x; o1.y += a1 * w.y; o1.z += a1 * w.z; o1.w += a1 * w.w;
    o2.x += a2 * w.x; o2.y += a2 * w.y; o2.z += a2 * w.z; o2.w += a2 * w.w;
    o3.x += a3 * w.x; o3.y += a3 * w.y; o3.z += a3 * w.z; o3.w += a3 * w.w;
  }
  float4* out4 = (float4*)(out_v + (size_t)(row0 + ty * 4) * DIM);
  out4[0 * 32 + tx] = o0;
  out4[1 * 32 + tx] = o1;
  out4[2 * 32 + tx] = o2;
  out4[3 * 32 + tx] = o3;
}

extern "C" void kernel_launch(void* const* d_in, const int* in_sizes, int n_in,
                              void* d_out, int out_size, void* d_ws, size_t ws_size,
                              hipStream_t stream) {
  const float* x      = (const float*)d_in[0];
  const float* inc    = (const float*)d_in[1];
  const int*   orders = (const int*)d_in[2];
  const float* norm   = (const float*)d_in[3];
  const float* W      = (const float*)d_in[4];
  const float* Bb     = (const float*)d_in[5];
  float* out_v = (float*)d_out;
  float* out_e = (float*)d_out + (size_t)NN * DIM;

  char* ws = (char*)d_ws;
  uint16_t* xhi   = (uint16_t*)(ws + WS_XHI);
  float* colsum   = (float*)(ws + WS_COLSUM);
  float* c0e      = (float*)(ws + WS_C0E);
  float* part     = (float*)(ws + WS_PART);

  k_prep<<<128, 256, 0, stream>>>(x, xhi, colsum);
  k_c0e<<<NL, 128, 0, stream>>>(colsum, W, Bb, c0e);
  k_gemm<<<512, 256, 0, stream>>>(inc, xhi, part);
  k_edge2<<<NE, 128, 0, stream>>>(part, orders, norm, W, c0e, out_e);
  k_node<<<NN / 32, 256, 0, stream>>>(x, W, c0e, out_v);
}